// Round 4
// baseline (190.268 us; speedup 1.0000x reference)
//
#include <hip/hip_runtime.h>
#include <math.h>

// Problem constants (fixed by the reference)
#define BG     64      // b*g = 2*32 groups
#define NN     2048    // nodes per group
#define F      128     // IN_F == 2*OUT_F == 128
#define OUTF   64      // OUT_F
#define NSLICE 16      // node slices per group

// Workspace layout (float offsets)
#define OFF_FP   0                           // [BG*NSLICE][4][128] partial pools
#define OFF_LP   (BG * NSLICE * 4 * F)       // [BG*NSLICE][4] partial exp-sums
#define OFF_CNT  (OFF_LP + BG * NSLICE * 4)  // [BG] int counters (zeroed per call)

// ---------------------------------------------------------------------------
// Single fused kernel.
// Phase 0: per-block redundant w_eff = W_h @ a_h into LDS (L2-hot reads).
// Phase 1: half-wave per node; float4 loads; head-interleaved butterfly
//          (6 shuffles) -> score of head (lane&3) on every lane; 1 exp;
//          3 shuffles rebroadcast; head-permuted accumulators.
// Phase 2: LDS combine across 8 half-waves; write slice partials to ws.
// Phase 3: per-group last-block-done -> matvec tail + ELU + store.
// ---------------------------------------------------------------------------
__global__ __launch_bounds__(256) void k_fused(
    const float* __restrict__ feat,
    const float* __restrict__ W1, const float* __restrict__ a1,
    const float* __restrict__ W2, const float* __restrict__ a2,
    const float* __restrict__ W3, const float* __restrict__ a3,
    const float* __restrict__ W4, const float* __restrict__ a4,
    const float* __restrict__ Wo,
    float* __restrict__ ws, float* __restrict__ out) {
  int g = blockIdx.x >> 4;
  int slice = blockIdx.x & (NSLICE - 1);
  int t = threadIdx.x;
  int lane = t & 31;   // i-chunk (float4) within a node row
  int hw = t >> 5;     // half-wave id, 0..7

  __shared__ float weff[4][F];
  __shared__ float4 part[8][4][32];
  __shared__ float sume[8][4];
  __shared__ int isLast;
  __shared__ float fpL[512];
  __shared__ float multi[512];
  __shared__ float invl[4];
  __shared__ float fpart[4][64];

  // ---- Phase 0: w_eff (each thread does 2 of the 512 (h,i) outputs) ----
  {
    int idx = t;
#pragma unroll
    for (int r = 0; r < 2; ++r, idx += 256) {
      int h = idx >> 7, i = idx & 127;
      const float* W = (h == 0) ? W1 : (h == 1) ? W2 : (h == 2) ? W3 : W4;
      const float* a = (h == 0) ? a1 : (h == 1) ? a2 : (h == 2) ? a3 : a4;
      float acc = 0.f;
#pragma unroll 16
      for (int j = 0; j < F; ++j) acc += W[i * F + j] * a[j];
      weff[h][i] = acc;
    }
  }
  __syncthreads();

  float4 w4[4];
#pragma unroll
  for (int h = 0; h < 4; ++h) w4[h] = ((const float4*)weff[h])[lane];

  // ---- Phase 1: fused score/exp/pool over this slice's 128 nodes ----
  const float* fbase = feat + ((size_t)g * NN + slice * (NN / NSLICE)) * F;
  float4 acc[4];
#pragma unroll
  for (int k = 0; k < 4; ++k) acc[k] = make_float4(0.f, 0.f, 0.f, 0.f);
  float se0 = 0.f;
  int l1 = lane & 1, l2 = lane & 2;

#pragma unroll 4
  for (int it = 0; it < (NN / NSLICE) / 8; ++it) {
    int n = it * 8 + hw;
    float4 f = ((const float4*)(fbase + (size_t)n * F))[lane];
    float p0 = f.x * w4[0].x + f.y * w4[0].y + f.z * w4[0].z + f.w * w4[0].w;
    float p1 = f.x * w4[1].x + f.y * w4[1].y + f.z * w4[1].z + f.w * w4[1].w;
    float p2 = f.x * w4[2].x + f.y * w4[2].y + f.z * w4[2].z + f.w * w4[2].w;
    float p3 = f.x * w4[3].x + f.y * w4[3].y + f.z * w4[3].z + f.w * w4[3].w;
    // Stage A (offset 1): merge heads {0,1} and {2,3}
    float a01 = l1 ? p1 : p0, b01 = l1 ? p0 : p1;
    a01 += __shfl_xor(b01, 1);
    float a23 = l1 ? p3 : p2, b23 = l1 ? p2 : p3;
    a23 += __shfl_xor(b23, 1);
    // Stage B (offset 2): merge pairs -> head (lane&3)
    float c = l2 ? a23 : a01, d = l2 ? a01 : a23;
    c += __shfl_xor(d, 2);
    // Stages C..E: plain butterfly on one value
    c += __shfl_xor(c, 4);
    c += __shfl_xor(c, 8);
    c += __shfl_xor(c, 16);
    // c = score of head (lane&3); exp once, rebroadcast 3x
    float e0 = __expf(c);
    float e1 = __shfl_xor(e0, 1);
    float e2 = __shfl_xor(e0, 2);
    float e3 = __shfl_xor(e0, 3);
    se0 += e0;  // head (lane&3); complete per node (value replicated)
    acc[0].x += e0 * f.x; acc[0].y += e0 * f.y; acc[0].z += e0 * f.z; acc[0].w += e0 * f.w;
    acc[1].x += e1 * f.x; acc[1].y += e1 * f.y; acc[1].z += e1 * f.z; acc[1].w += e1 * f.w;
    acc[2].x += e2 * f.x; acc[2].y += e2 * f.y; acc[2].z += e2 * f.z; acc[2].w += e2 * f.w;
    acc[3].x += e3 * f.x; acc[3].y += e3 * f.y; acc[3].z += e3 * f.z; acc[3].w += e3 * f.w;
  }

  // ---- Phase 2: un-permute heads into LDS, combine 8 half-waves ----
  int hbase = lane & 3;
#pragma unroll
  for (int k = 0; k < 4; ++k) part[hw][hbase ^ k][lane] = acc[k];
  if (lane < 4) sume[hw][lane] = se0;  // lane == head
  __syncthreads();

  if (t < 128) {
    int h = t >> 5, l = t & 31;
    float4 s = part[0][h][l];
#pragma unroll
    for (int q = 1; q < 8; ++q) {
      float4 o = part[q][h][l];
      s.x += o.x; s.y += o.y; s.z += o.z; s.w += o.w;
    }
    ((float4*)(ws + OFF_FP + ((size_t)(g * NSLICE + slice) * 4 + h) * F))[l] = s;
  }
  if (t < 4) {
    float s = 0.f;
#pragma unroll
    for (int q = 0; q < 8; ++q) s += sume[q][t];
    ws[OFF_LP + (g * NSLICE + slice) * 4 + t] = s;
  }
  __syncthreads();  // drains the ws stores (vmcnt) for the whole block

  // ---- Phase 3: last block of this group finishes the tail ----
  if (t == 0) {
    __threadfence();  // release: partials visible at agent scope
    int* cnt = (int*)(ws + OFF_CNT);
    int old = atomicAdd(&cnt[g], 1);
    isLast = (old == NSLICE - 1) ? 1 : 0;
  }
  __syncthreads();
  if (!isLast) return;
  if (t == 0) __threadfence();  // acquire: invalidate stale cached lines
  __syncthreads();

  // invl
  if (t < 4) {
    float s = 0.f;
#pragma unroll
    for (int sl = 0; sl < NSLICE; ++sl)
      s += ws[OFF_LP + (g * NSLICE + sl) * 4 + t];
    invl[t] = 1.0f / s;
  }
  // combine slice pools (512 outputs, 2 per thread)
  float sums[2];
#pragma unroll
  for (int r = 0; r < 2; ++r) {
    int idx = t + r * 256;
    const float* fpb = ws + OFF_FP + (size_t)g * NSLICE * 512 + idx;
    float s = 0.f;
#pragma unroll
    for (int sl = 0; sl < NSLICE; ++sl) s += fpb[sl * 512];
    sums[r] = s;
  }
  __syncthreads();  // invl ready
#pragma unroll
  for (int r = 0; r < 2; ++r) {
    int idx = t + r * 256;
    fpL[idx] = sums[r] * invl[idx >> 7];
  }
  __syncthreads();

  // Stage 1: multi[h*128+col] = fpL[h] . W_h[:,col]  (2 outputs per thread)
#pragma unroll
  for (int r = 0; r < 2; ++r) {
    int idx = t + r * 256;
    int h = idx >> 7, col = idx & 127;
    const float* W = (h == 0) ? W1 : (h == 1) ? W2 : (h == 2) ? W3 : W4;
    const float* fph = fpL + h * F;
    float acc2 = 0.f;
#pragma unroll 16
    for (int i = 0; i < F; ++i) acc2 += fph[i] * W[i * F + col];
    multi[idx] = acc2;
  }
  __syncthreads();

  // Stage 2: out[o] = elu(multi . Wo[:,o]); 4 chunks of 128 per column
  {
    int o = t & 63, chunk = t >> 6;
    const float* mk = multi + chunk * 128;
    const float* wk = Wo + (size_t)chunk * 128 * OUTF + o;
    float p = 0.f;
#pragma unroll 16
    for (int k = 0; k < 128; ++k) p += mk[k] * wk[k * OUTF];
    fpart[chunk][o] = p;
  }
  __syncthreads();

  if (t < 64) {
    float s = fpart[0][t] + fpart[1][t] + fpart[2][t] + fpart[3][t];
    out[g * OUTF + t] = (s > 0.f) ? s : expm1f(s);
  }
}

// ---------------------------------------------------------------------------
extern "C" void kernel_launch(void* const* d_in, const int* in_sizes, int n_in,
                              void* d_out, int out_size, void* d_ws, size_t ws_size,
                              hipStream_t stream) {
  const float* feat = (const float*)d_in[0];
  const float* W1 = (const float*)d_in[1];
  const float* a1 = (const float*)d_in[2];
  const float* W2 = (const float*)d_in[3];
  const float* a2 = (const float*)d_in[4];
  const float* W3 = (const float*)d_in[5];
  const float* a3 = (const float*)d_in[6];
  const float* W4 = (const float*)d_in[7];
  const float* a4 = (const float*)d_in[8];
  const float* Wo = (const float*)d_in[9];
  float* ws = (float*)d_ws;
  float* out = (float*)d_out;

  // zero the per-group arrival counters (ws is re-poisoned every call)
  hipMemsetAsync((char*)d_ws + OFF_CNT * sizeof(float), 0,
                 BG * sizeof(int), stream);

  k_fused<<<BG * NSLICE, 256, 0, stream>>>(feat, W1, a1, W2, a2, W3, a3,
                                           W4, a4, Wo, ws, out);
}

// Round 5
// 165.564 us; speedup vs baseline: 1.1492x; 1.1492x over previous
//
#include <hip/hip_runtime.h>
#include <math.h>

// Problem constants (fixed by the reference)
#define BG     64      // b*g = 2*32 groups
#define NN     2048    // nodes per group
#define F      128     // IN_F == 2*OUT_F == 128
#define OUTF   64      // OUT_F
#define NSLICE 16      // node slices per group

// Workspace layout (float offsets)
#define OFF_WEFF 0                                  // [4][128]
#define OFF_FP   512                                // [BG*NSLICE][4][128] partial pools
#define OFF_LP   (512 + BG * NSLICE * 4 * F)        // [BG*NSLICE][4] partial exp-sums
#define OFF_CNT  (OFF_LP + BG * NSLICE * 4)         // [BG] int counters (zeroed per call)

// ---------------------------------------------------------------------------
// K1: w_eff[h][i] = sum_j W_h[i][j] * a_h[j]   (512 threads, ONE block).
// Uncoalesced W-row reads are fine exactly once; running this per-block in
// R4 cost ~4.3 GB of L2 traffic (16x line amplification x 1024 blocks).
// ---------------------------------------------------------------------------
__global__ __launch_bounds__(512) void k_weff(
    const float* __restrict__ W1, const float* __restrict__ a1,
    const float* __restrict__ W2, const float* __restrict__ a2,
    const float* __restrict__ W3, const float* __restrict__ a3,
    const float* __restrict__ W4, const float* __restrict__ a4,
    float* __restrict__ ws) {
  int t = threadIdx.x;          // 0..511
  int h = t >> 7, i = t & 127;
  const float* W = (h == 0) ? W1 : (h == 1) ? W2 : (h == 2) ? W3 : W4;
  const float* a = (h == 0) ? a1 : (h == 1) ? a2 : (h == 2) ? a3 : a4;
  float acc = 0.f;
#pragma unroll 16
  for (int j = 0; j < F; ++j) acc += W[i * F + j] * a[j];
  ws[OFF_WEFF + h * F + i] = acc;
}

// ---------------------------------------------------------------------------
// K2: fused score/exp/pool pass + per-group last-block-done matvec tail.
// Half-wave per node; float4 loads; head-interleaved butterfly (6 shuffles)
// -> score of head (lane&3) on every lane; 1 exp; 3 shuffles rebroadcast;
// head-permuted accumulators, un-permuted at the LDS write.
// ---------------------------------------------------------------------------
__global__ __launch_bounds__(256) void k_fused(
    const float* __restrict__ feat,
    const float* __restrict__ W1, const float* __restrict__ W2,
    const float* __restrict__ W3, const float* __restrict__ W4,
    const float* __restrict__ Wo,
    float* __restrict__ ws, float* __restrict__ out) {
  int g = blockIdx.x >> 4;
  int slice = blockIdx.x & (NSLICE - 1);
  int t = threadIdx.x;
  int lane = t & 31;   // i-chunk (float4) within a node row
  int hw = t >> 5;     // half-wave id, 0..7

  __shared__ float4 part[8][4][32];
  __shared__ float sume[8][4];
  __shared__ int isLast;
  __shared__ float fpL[512];
  __shared__ float multi[512];
  __shared__ float invl[4];
  __shared__ float fpart[4][64];

  // w_eff fragments: coalesced float4 per lane, L2-broadcast (same addrs
  // across half-waves)
  float4 w4[4];
#pragma unroll
  for (int h = 0; h < 4; ++h)
    w4[h] = ((const float4*)(ws + OFF_WEFF + h * F))[lane];

  // ---- Phase 1: fused score/exp/pool over this slice's 128 nodes ----
  const float* fbase = feat + ((size_t)g * NN + slice * (NN / NSLICE)) * F;
  float4 acc[4];
#pragma unroll
  for (int k = 0; k < 4; ++k) acc[k] = make_float4(0.f, 0.f, 0.f, 0.f);
  float se0 = 0.f;
  int l1 = lane & 1, l2 = lane & 2;

#pragma unroll 4
  for (int it = 0; it < (NN / NSLICE) / 8; ++it) {
    int n = it * 8 + hw;
    float4 f = ((const float4*)(fbase + (size_t)n * F))[lane];
    float p0 = f.x * w4[0].x + f.y * w4[0].y + f.z * w4[0].z + f.w * w4[0].w;
    float p1 = f.x * w4[1].x + f.y * w4[1].y + f.z * w4[1].z + f.w * w4[1].w;
    float p2 = f.x * w4[2].x + f.y * w4[2].y + f.z * w4[2].z + f.w * w4[2].w;
    float p3 = f.x * w4[3].x + f.y * w4[3].y + f.z * w4[3].z + f.w * w4[3].w;
    // Stage A (offset 1): merge heads {0,1} and {2,3}
    float a01 = l1 ? p1 : p0, b01 = l1 ? p0 : p1;
    a01 += __shfl_xor(b01, 1);
    float a23 = l1 ? p3 : p2, b23 = l1 ? p2 : p3;
    a23 += __shfl_xor(b23, 1);
    // Stage B (offset 2): merge pairs -> head (lane&3)
    float c = l2 ? a23 : a01, d = l2 ? a01 : a23;
    c += __shfl_xor(d, 2);
    // Stages C..E: plain butterfly on one value
    c += __shfl_xor(c, 4);
    c += __shfl_xor(c, 8);
    c += __shfl_xor(c, 16);
    // c = score of head (lane&3); exp once, rebroadcast 3x.
    // No max-subtraction: Xavier-bounded scores keep exp() in fp32 range.
    float e0 = __expf(c);
    float e1 = __shfl_xor(e0, 1);
    float e2 = __shfl_xor(e0, 2);
    float e3 = __shfl_xor(e0, 3);
    se0 += e0;  // head (lane&3); complete per node (value replicated)
    acc[0].x += e0 * f.x; acc[0].y += e0 * f.y; acc[0].z += e0 * f.z; acc[0].w += e0 * f.w;
    acc[1].x += e1 * f.x; acc[1].y += e1 * f.y; acc[1].z += e1 * f.z; acc[1].w += e1 * f.w;
    acc[2].x += e2 * f.x; acc[2].y += e2 * f.y; acc[2].z += e2 * f.z; acc[2].w += e2 * f.w;
    acc[3].x += e3 * f.x; acc[3].y += e3 * f.y; acc[3].z += e3 * f.z; acc[3].w += e3 * f.w;
  }

  // ---- Phase 2: un-permute heads into LDS, combine 8 half-waves ----
  int hbase = lane & 3;
#pragma unroll
  for (int k = 0; k < 4; ++k) part[hw][hbase ^ k][lane] = acc[k];
  if (lane < 4) sume[hw][lane] = se0;  // lane == head
  __syncthreads();

  if (t < 128) {
    int h = t >> 5, l = t & 31;
    float4 s = part[0][h][l];
#pragma unroll
    for (int q = 1; q < 8; ++q) {
      float4 o = part[q][h][l];
      s.x += o.x; s.y += o.y; s.z += o.z; s.w += o.w;
    }
    ((float4*)(ws + OFF_FP + ((size_t)(g * NSLICE + slice) * 4 + h) * F))[l] = s;
  }
  if (t < 4) {
    float s = 0.f;
#pragma unroll
    for (int q = 0; q < 8; ++q) s += sume[q][t];
    ws[OFF_LP + (g * NSLICE + slice) * 4 + t] = s;
  }
  __syncthreads();  // drains the ws stores (vmcnt) for the whole block

  // ---- Phase 3: last block of this group finishes the tail ----
  if (t == 0) {
    __threadfence();  // release: partials visible at device scope
    int* cnt = (int*)(ws + OFF_CNT);
    int old = atomicAdd(&cnt[g], 1);
    isLast = (old == NSLICE - 1) ? 1 : 0;
  }
  __syncthreads();
  if (!isLast) return;
  if (t == 0) __threadfence();  // acquire: invalidate stale cached lines
  __syncthreads();

  // invl
  if (t < 4) {
    float s = 0.f;
#pragma unroll
    for (int sl = 0; sl < NSLICE; ++sl)
      s += ws[OFF_LP + (g * NSLICE + sl) * 4 + t];
    invl[t] = 1.0f / s;
  }
  // combine slice pools (512 outputs, 2 per thread)
  float sums[2];
#pragma unroll
  for (int r = 0; r < 2; ++r) {
    int idx = t + r * 256;
    const float* fpb = ws + OFF_FP + (size_t)g * NSLICE * 512 + idx;
    float s = 0.f;
#pragma unroll
    for (int sl = 0; sl < NSLICE; ++sl) s += fpb[sl * 512];
    sums[r] = s;
  }
  __syncthreads();  // invl ready
#pragma unroll
  for (int r = 0; r < 2; ++r) {
    int idx = t + r * 256;
    fpL[idx] = sums[r] * invl[idx >> 7];
  }
  __syncthreads();

  // Stage 1: multi[h*128+col] = fpL[h] . W_h[:,col]  (2 outputs per thread)
#pragma unroll
  for (int r = 0; r < 2; ++r) {
    int idx = t + r * 256;
    int h = idx >> 7, col = idx & 127;
    const float* W = (h == 0) ? W1 : (h == 1) ? W2 : (h == 2) ? W3 : W4;
    const float* fph = fpL + h * F;
    float acc2 = 0.f;
#pragma unroll 16
    for (int i = 0; i < F; ++i) acc2 += fph[i] * W[i * F + col];
    multi[idx] = acc2;
  }
  __syncthreads();

  // Stage 2: out[o] = elu(multi . Wo[:,o]); 4 chunks of 128 per column
  {
    int o = t & 63, chunk = t >> 6;
    const float* mk = multi + chunk * 128;
    const float* wk = Wo + (size_t)chunk * 128 * OUTF + o;
    float p = 0.f;
#pragma unroll 16
    for (int k = 0; k < 128; ++k) p += mk[k] * wk[k * OUTF];
    fpart[chunk][o] = p;
  }
  __syncthreads();

  if (t < 64) {
    float s = fpart[0][t] + fpart[1][t] + fpart[2][t] + fpart[3][t];
    out[g * OUTF + t] = (s > 0.f) ? s : expm1f(s);
  }
}

// ---------------------------------------------------------------------------
extern "C" void kernel_launch(void* const* d_in, const int* in_sizes, int n_in,
                              void* d_out, int out_size, void* d_ws, size_t ws_size,
                              hipStream_t stream) {
  const float* feat = (const float*)d_in[0];
  const float* W1 = (const float*)d_in[1];
  const float* a1 = (const float*)d_in[2];
  const float* W2 = (const float*)d_in[3];
  const float* a2 = (const float*)d_in[4];
  const float* W3 = (const float*)d_in[5];
  const float* a3 = (const float*)d_in[6];
  const float* W4 = (const float*)d_in[7];
  const float* a4 = (const float*)d_in[8];
  const float* Wo = (const float*)d_in[9];
  float* ws = (float*)d_ws;
  float* out = (float*)d_out;

  // zero the per-group arrival counters (ws is re-poisoned every call)
  hipMemsetAsync((char*)d_ws + OFF_CNT * sizeof(float), 0,
                 BG * sizeof(int), stream);

  k_weff<<<1, 512, 0, stream>>>(W1, a1, W2, a2, W3, a3, W4, a4, ws);
  k_fused<<<BG * NSLICE, 256, 0, stream>>>(feat, W1, W2, W3, W4, Wo, ws, out);
}

// Round 6
// 133.289 us; speedup vs baseline: 1.4275x; 1.2421x over previous
//
#include <hip/hip_runtime.h>
#include <math.h>

// Problem constants (fixed by the reference)
#define BG     64      // b*g = 2*32 groups
#define NN     2048    // nodes per group
#define F      128     // IN_F == 2*OUT_F == 128
#define OUTF   64      // OUT_F
#define NSLICE 16      // node slices per group (128 nodes each)

// Workspace layout (float offsets)
#define OFF_WEFF 0                                  // [4][128]
#define OFF_FP   512                                // [BG*NSLICE][4][128] partial pools
#define OFF_LP   (512 + BG * NSLICE * 4 * F)        // [BG*NSLICE][4] partial exp-sums

// ---------------------------------------------------------------------------
// K1: w_eff[h][i] = sum_j W_h[i][j] * a_h[j]   (512 threads, ONE block).
// score_n = (feat_n @ W) . a = feat_n . (W @ a); pooled = (sum p_n feat_n) @ W
// ---------------------------------------------------------------------------
__global__ __launch_bounds__(512) void k_weff(
    const float* __restrict__ W1, const float* __restrict__ a1,
    const float* __restrict__ W2, const float* __restrict__ a2,
    const float* __restrict__ W3, const float* __restrict__ a3,
    const float* __restrict__ W4, const float* __restrict__ a4,
    float* __restrict__ ws) {
  int t = threadIdx.x;          // 0..511
  int h = t >> 7, i = t & 127;
  const float* W = (h == 0) ? W1 : (h == 1) ? W2 : (h == 2) ? W3 : W4;
  const float* a = (h == 0) ? a1 : (h == 1) ? a2 : (h == 2) ? a3 : a4;
  float acc = 0.f;
#pragma unroll 16
  for (int j = 0; j < F; ++j) acc += W[i * F + j] * a[j];
  ws[OFF_WEFF + h * F + i] = acc;
}

// ---------------------------------------------------------------------------
// K2: per-slice fused score/exp/pool with LDS staging. No shuffles, no
// fences, no atomics. XOR chunk swizzle (c ^ (n&31)) keeps every b128 LDS
// access conflict-free across all three stages.
// Stage 1: 16 independent coalesced float4 loads/thread -> swizzled LDS.
// Stage 2: thread t<128 owns node t: 4 head dots from LDS + 4 exps -> eL.
// Stage 3: thread (i4,q) pools its node-quarter; LDS combine; -> ws.
// ---------------------------------------------------------------------------
__global__ __launch_bounds__(256) void k_main(
    const float* __restrict__ feat, float* __restrict__ ws) {
  int g = blockIdx.x >> 4;
  int slice = blockIdx.x & (NSLICE - 1);
  int t = threadIdx.x;

  __shared__ float4 sfeat[128 * 32];   // row n chunk c stored at n*32 + (c^(n&31))
  __shared__ float4 weffL[4 * 32];     // w_eff[h] chunk c at h*32 + c
  __shared__ float4 eL[128];           // exp(scores) per node, 4 heads
  __shared__ float4 pacc[4][4][32];    // [h][q][i4] quarter partials
  __shared__ float4 sePart[4];         // per-quarter exp-sum partials

  if (t < 128) weffL[t] = ((const float4*)(ws + OFF_WEFF))[t];

  // ---- Stage 1: global -> LDS (swizzled), max memory-level parallelism ----
  const float4* fb =
      (const float4*)(feat + ((size_t)g * NN + slice * 128) * F);
  float4 ld[16];
#pragma unroll
  for (int k = 0; k < 16; ++k) ld[k] = fb[k * 256 + t];
#pragma unroll
  for (int k = 0; k < 16; ++k) {
    int j = k * 256 + t;
    int n = j >> 5, c = j & 31;
    sfeat[n * 32 + (c ^ (n & 31))] = ld[k];
  }
  __syncthreads();

  // ---- Stage 2: node-per-thread dots + exp (no cross-lane reduction) ----
  if (t < 128) {
    int n = t, sw = n & 31, base = n * 32;
    float p0 = 0.f, p1 = 0.f, p2 = 0.f, p3 = 0.f;
#pragma unroll 8
    for (int c = 0; c < 32; ++c) {
      float4 f = sfeat[base + (c ^ sw)];
      float4 w0 = weffL[c], w1 = weffL[32 + c], w2 = weffL[64 + c],
             w3 = weffL[96 + c];
      p0 += f.x * w0.x + f.y * w0.y + f.z * w0.z + f.w * w0.w;
      p1 += f.x * w1.x + f.y * w1.y + f.z * w1.z + f.w * w1.w;
      p2 += f.x * w2.x + f.y * w2.y + f.z * w2.z + f.w * w2.w;
      p3 += f.x * w3.x + f.y * w3.y + f.z * w3.z + f.w * w3.w;
    }
    // No max-subtraction: Xavier-bounded scores keep exp() in fp32 range.
    eL[n] = make_float4(__expf(p0), __expf(p1), __expf(p2), __expf(p3));
  }
  __syncthreads();

  // ---- Stage 3: pool e*feat over node quarters, thread = (i4, q) ----
  if (t < 128) {
    int i4 = t & 31, q = t >> 5;
    float4 a0 = make_float4(0.f, 0.f, 0.f, 0.f), a1 = a0, a2 = a0, a3 = a0;
    float4 se = a0;
#pragma unroll 8
    for (int nn = 0; nn < 32; ++nn) {
      int n = q * 32 + nn;
      float4 f = sfeat[n * 32 + (i4 ^ (n & 31))];
      float4 e = eL[n];
      a0.x += e.x * f.x; a0.y += e.x * f.y; a0.z += e.x * f.z; a0.w += e.x * f.w;
      a1.x += e.y * f.x; a1.y += e.y * f.y; a1.z += e.y * f.z; a1.w += e.y * f.w;
      a2.x += e.z * f.x; a2.y += e.z * f.y; a2.z += e.z * f.z; a2.w += e.z * f.w;
      a3.x += e.w * f.x; a3.y += e.w * f.y; a3.z += e.w * f.z; a3.w += e.w * f.w;
      se.x += e.x; se.y += e.y; se.z += e.z; se.w += e.w;
    }
    pacc[0][q][i4] = a0; pacc[1][q][i4] = a1;
    pacc[2][q][i4] = a2; pacc[3][q][i4] = a3;
    if (i4 == 0) sePart[q] = se;
  }
  __syncthreads();

  // ---- Combine quarters, write slice partials to ws ----
  if (t < 128) {
    int i4 = t & 31, h = t >> 5;
    float4 s0 = pacc[h][0][i4], s1 = pacc[h][1][i4];
    float4 s2 = pacc[h][2][i4], s3 = pacc[h][3][i4];
    float4 s = make_float4(s0.x + s1.x + s2.x + s3.x,
                           s0.y + s1.y + s2.y + s3.y,
                           s0.z + s1.z + s2.z + s3.z,
                           s0.w + s1.w + s2.w + s3.w);
    ((float4*)(ws + OFF_FP))[(size_t)(g * NSLICE + slice) * 128 + h * 32 + i4] = s;
  }
  if (t == 0) {
    float4 L = make_float4(
        sePart[0].x + sePart[1].x + sePart[2].x + sePart[3].x,
        sePart[0].y + sePart[1].y + sePart[2].y + sePart[3].y,
        sePart[0].z + sePart[1].z + sePart[2].z + sePart[3].z,
        sePart[0].w + sePart[1].w + sePart[2].w + sePart[3].w);
    ((float4*)(ws + OFF_LP))[g * NSLICE + slice] = L;
  }
}

// ---------------------------------------------------------------------------
// K3: combine slice partials, normalize, pooled@W_h, concat@Wo, ELU.
// One block (512 threads) per group.
// ---------------------------------------------------------------------------
__global__ __launch_bounds__(512) void k_final(
    const float* __restrict__ W1, const float* __restrict__ W2,
    const float* __restrict__ W3, const float* __restrict__ W4,
    const float* __restrict__ Wo, const float* __restrict__ ws,
    float* __restrict__ out) {
  int g = blockIdx.x;
  int t = threadIdx.x;  // 0..511
  __shared__ float fp[512];
  __shared__ float multi[512];
  __shared__ float invl[4];
  __shared__ float part[8][64];

  if (t < 4) {
    float s = 0.f;
#pragma unroll
    for (int sl = 0; sl < NSLICE; ++sl)
      s += ws[OFF_LP + (g * NSLICE + sl) * 4 + t];
    invl[t] = 1.0f / s;
  }
  float s = 0.f;
  const float* fpb = ws + OFF_FP + (size_t)g * NSLICE * 512 + t;
#pragma unroll
  for (int sl = 0; sl < NSLICE; ++sl) s += fpb[sl * 512];
  __syncthreads();               // invl ready
  fp[t] = s * invl[t >> 7];      // pooled feature vector, normalized
  __syncthreads();

  // Stage 1: multi[h*128+col] = fp[h] . W_h[:,col]
  int h = t >> 7, col = t & 127;
  const float* W = (h == 0) ? W1 : (h == 1) ? W2 : (h == 2) ? W3 : W4;
  const float* fph = fp + h * F;
  float acc = 0.f;
#pragma unroll 16
  for (int i = 0; i < F; ++i) acc += fph[i] * W[i * F + col];
  multi[t] = acc;
  __syncthreads();

  // Stage 2: out[o] = elu(multi . Wo[:,o]); 8 partials per output column
  int o = t & 63, chunk = t >> 6;
  const float* mk = multi + chunk * 64;
  const float* wk = Wo + (size_t)chunk * 64 * OUTF + o;
  float p = 0.f;
#pragma unroll 16
  for (int k = 0; k < 64; ++k) p += mk[k] * wk[k * OUTF];
  part[chunk][o] = p;
  __syncthreads();

  if (t < 64) {
    float acc2 = 0.f;
#pragma unroll
    for (int c = 0; c < 8; ++c) acc2 += part[c][t];
    out[g * OUTF + t] = (acc2 > 0.f) ? acc2 : expm1f(acc2);
  }
}

// ---------------------------------------------------------------------------
extern "C" void kernel_launch(void* const* d_in, const int* in_sizes, int n_in,
                              void* d_out, int out_size, void* d_ws, size_t ws_size,
                              hipStream_t stream) {
  const float* feat = (const float*)d_in[0];
  const float* W1 = (const float*)d_in[1];
  const float* a1 = (const float*)d_in[2];
  const float* W2 = (const float*)d_in[3];
  const float* a2 = (const float*)d_in[4];
  const float* W3 = (const float*)d_in[5];
  const float* a3 = (const float*)d_in[6];
  const float* W4 = (const float*)d_in[7];
  const float* a4 = (const float*)d_in[8];
  const float* Wo = (const float*)d_in[9];
  float* ws = (float*)d_ws;
  float* out = (float*)d_out;

  k_weff<<<1, 512, 0, stream>>>(W1, a1, W2, a2, W3, a3, W4, a4, ws);
  k_main<<<BG * NSLICE, 256, 0, stream>>>(feat, ws);
  k_final<<<BG, 512, 0, stream>>>(W1, W2, W3, W4, Wo, ws, out);
}

// Round 7
// 121.639 us; speedup vs baseline: 1.5642x; 1.0958x over previous
//
#include <hip/hip_runtime.h>
#include <math.h>

// Problem constants (fixed by the reference)
#define BG     64      // b*g = 2*32 groups
#define NN     2048    // nodes per group
#define F      128     // IN_F == 2*OUT_F == 128
#define OUTF   64      // OUT_F
#define NSLICE 16      // node slices per group (128 nodes each)

// Workspace layout (float offsets)
#define OFF_WEFF 0                                  // [4][128]
#define OFF_FP   512                                // [BG*NSLICE][4][128] partial pools
#define OFF_LP   (512 + BG * NSLICE * 4 * F)        // [BG*NSLICE][4] partial exp-sums

// ---------------------------------------------------------------------------
// K1: w_eff[h] = W_h @ a_h. One block per head, fully coalesced float4 W
// reads (R4 lesson: row-per-thread W reads are 16x line-amplified).
// score_n = (feat_n @ W) . a = feat_n . (W @ a); pooled = (sum p_n feat_n) @ W
// ---------------------------------------------------------------------------
__global__ __launch_bounds__(256) void k_weff(
    const float* __restrict__ W1, const float* __restrict__ a1,
    const float* __restrict__ W2, const float* __restrict__ a2,
    const float* __restrict__ W3, const float* __restrict__ a3,
    const float* __restrict__ W4, const float* __restrict__ a4,
    float* __restrict__ ws) {
  int h = blockIdx.x, t = threadIdx.x;
  const float* W = (h == 0) ? W1 : (h == 1) ? W2 : (h == 2) ? W3 : W4;
  const float* a = (h == 0) ? a1 : (h == 1) ? a2 : (h == 2) ? a3 : a4;
  __shared__ float aL[F];
  __shared__ float part[F][33];   // +1 pad: conflict-free row sums

  if (t < F) aL[t] = a[t];
  __syncthreads();

  int c = t & 31, r8 = t >> 5;    // chunk, row-octet
#pragma unroll
  for (int it = 0; it < 16; ++it) {
    int row = it * 8 + r8;
    float4 w = ((const float4*)(W + row * F))[c];
    part[row][c] = w.x * aL[4 * c] + w.y * aL[4 * c + 1] +
                   w.z * aL[4 * c + 2] + w.w * aL[4 * c + 3];
  }
  __syncthreads();

  if (t < F) {
    float s = 0.f;
#pragma unroll
    for (int c2 = 0; c2 < 32; ++c2) s += part[t][c2];
    ws[OFF_WEFF + h * F + t] = s;
  }
}

// ---------------------------------------------------------------------------
// K2: per-slice fused score/exp/pool with swizzled LDS staging. All 256
// threads active in every stage. XOR chunk swizzle (c ^ (n&31)) keeps every
// b128 LDS access at <=2 lanes/bank-quad (free) across all stages.
// Stage 1: 16 independent coalesced float4 loads/thread -> swizzled LDS.
// Stage 2: thread (n, head-pair): 2 head dots + 2 exps -> eLf.
// Stage 3: thread (i4, quarter, head-pair): pool 2 heads over 32 nodes.
// ---------------------------------------------------------------------------
__global__ __launch_bounds__(256) void k_main(
    const float* __restrict__ feat, float* __restrict__ ws) {
  int g = blockIdx.x >> 4;
  int slice = blockIdx.x & (NSLICE - 1);
  int t = threadIdx.x;

  __shared__ float4 sfeat[128 * 32];  // row n chunk c at n*32 + (c^(n&31))
  __shared__ float4 weffL[4 * 32];    // w_eff[h] chunk c at h*32 + c
  __shared__ float eLf[128 * 4];      // exp(score) [node][head]
  __shared__ float4 pacc[4][4][32];   // [head][quarter][i4]
  __shared__ float sePf[4][4];        // [quarter][head] exp-sum partials

  if (t < 128) weffL[t] = ((const float4*)(ws + OFF_WEFF))[t];

  // ---- Stage 1: global -> LDS (swizzled), max memory-level parallelism ----
  const float4* fb =
      (const float4*)(feat + ((size_t)g * NN + slice * 128) * F);
  float4 ld[16];
#pragma unroll
  for (int k = 0; k < 16; ++k) ld[k] = fb[k * 256 + t];
#pragma unroll
  for (int k = 0; k < 16; ++k) {
    int j = k * 256 + t;
    int n = j >> 5, c = j & 31;
    sfeat[n * 32 + (c ^ (n & 31))] = ld[k];
  }
  __syncthreads();

  // ---- Stage 2: thread (n, half) computes 2 head dots + exps ----
  {
    int n = t & 127, half = t >> 7;
    int sw = n & 31, base = n * 32, wb = half * 64;
    float pa = 0.f, pb = 0.f;
#pragma unroll 8
    for (int c = 0; c < 32; ++c) {
      float4 f = sfeat[base + (c ^ sw)];
      float4 wa = weffL[wb + c], wbv = weffL[wb + 32 + c];
      pa += f.x * wa.x + f.y * wa.y + f.z * wa.z + f.w * wa.w;
      pb += f.x * wbv.x + f.y * wbv.y + f.z * wbv.z + f.w * wbv.w;
    }
    // No max-subtraction: Xavier-bounded scores keep exp() in fp32 range.
    *(float2*)&eLf[n * 4 + half * 2] = make_float2(__expf(pa), __expf(pb));
  }
  __syncthreads();

  // ---- Stage 3: thread (i4, q, hh) pools 2 heads over its node quarter ----
  {
    int i4 = t & 31, q = (t >> 5) & 3, hh = t >> 7;
    float4 a0 = make_float4(0.f, 0.f, 0.f, 0.f), a1 = a0;
    float sex = 0.f, sey = 0.f;
#pragma unroll 8
    for (int nn = 0; nn < 32; ++nn) {
      int n = q * 32 + nn;
      float4 f = sfeat[n * 32 + (i4 ^ (n & 31))];
      float2 e = *(const float2*)&eLf[n * 4 + hh * 2];
      a0.x += e.x * f.x; a0.y += e.x * f.y; a0.z += e.x * f.z; a0.w += e.x * f.w;
      a1.x += e.y * f.x; a1.y += e.y * f.y; a1.z += e.y * f.z; a1.w += e.y * f.w;
      sex += e.x; sey += e.y;
    }
    pacc[hh * 2][q][i4] = a0;
    pacc[hh * 2 + 1][q][i4] = a1;
    if (i4 == 0) { sePf[q][hh * 2] = sex; sePf[q][hh * 2 + 1] = sey; }
  }
  __syncthreads();

  // ---- Combine quarters, write slice partials to ws ----
  if (t < 128) {
    int i4 = t & 31, h = t >> 5;
    float4 s0 = pacc[h][0][i4], s1 = pacc[h][1][i4];
    float4 s2 = pacc[h][2][i4], s3 = pacc[h][3][i4];
    float4 s = make_float4(s0.x + s1.x + s2.x + s3.x,
                           s0.y + s1.y + s2.y + s3.y,
                           s0.z + s1.z + s2.z + s3.z,
                           s0.w + s1.w + s2.w + s3.w);
    ((float4*)(ws + OFF_FP))[(size_t)(g * NSLICE + slice) * 128 + h * 32 + i4] = s;
  }
  if (t == 0) {
    float4 L = make_float4(
        sePf[0][0] + sePf[1][0] + sePf[2][0] + sePf[3][0],
        sePf[0][1] + sePf[1][1] + sePf[2][1] + sePf[3][1],
        sePf[0][2] + sePf[1][2] + sePf[2][2] + sePf[3][2],
        sePf[0][3] + sePf[1][3] + sePf[2][3] + sePf[3][3]);
    ((float4*)(ws + OFF_LP))[g * NSLICE + slice] = L;
  }
}

// ---------------------------------------------------------------------------
// K3: combine slice partials, normalize, pooled@W_h, concat@Wo, ELU.
// One block (512 threads) per group.
// ---------------------------------------------------------------------------
__global__ __launch_bounds__(512) void k_final(
    const float* __restrict__ W1, const float* __restrict__ W2,
    const float* __restrict__ W3, const float* __restrict__ W4,
    const float* __restrict__ Wo, const float* __restrict__ ws,
    float* __restrict__ out) {
  int g = blockIdx.x;
  int t = threadIdx.x;  // 0..511
  __shared__ float fp[512];
  __shared__ float multi[512];
  __shared__ float invl[4];
  __shared__ float part[8][64];

  if (t < 4) {
    float s = 0.f;
#pragma unroll
    for (int sl = 0; sl < NSLICE; ++sl)
      s += ws[OFF_LP + (g * NSLICE + sl) * 4 + t];
    invl[t] = 1.0f / s;
  }
  float s = 0.f;
  const float* fpb = ws + OFF_FP + (size_t)g * NSLICE * 512 + t;
#pragma unroll
  for (int sl = 0; sl < NSLICE; ++sl) s += fpb[sl * 512];
  __syncthreads();               // invl ready
  fp[t] = s * invl[t >> 7];      // pooled feature vector, normalized
  __syncthreads();

  // Stage 1: multi[h*128+col] = fp[h] . W_h[:,col]
  int h = t >> 7, col = t & 127;
  const float* W = (h == 0) ? W1 : (h == 1) ? W2 : (h == 2) ? W3 : W4;
  const float* fph = fp + h * F;
  float acc = 0.f;
#pragma unroll 16
  for (int i = 0; i < F; ++i) acc += fph[i] * W[i * F + col];
  multi[t] = acc;
  __syncthreads();

  // Stage 2: out[o] = elu(multi . Wo[:,o]); 8 partials per output column
  int o = t & 63, chunk = t >> 6;
  const float* mk = multi + chunk * 64;
  const float* wk = Wo + (size_t)chunk * 64 * OUTF + o;
  float p = 0.f;
#pragma unroll 16
  for (int k = 0; k < 64; ++k) p += mk[k] * wk[k * OUTF];
  part[chunk][o] = p;
  __syncthreads();

  if (t < 64) {
    float acc2 = 0.f;
#pragma unroll
    for (int c = 0; c < 8; ++c) acc2 += part[c][t];
    out[g * OUTF + t] = (acc2 > 0.f) ? acc2 : expm1f(acc2);
  }
}

// ---------------------------------------------------------------------------
extern "C" void kernel_launch(void* const* d_in, const int* in_sizes, int n_in,
                              void* d_out, int out_size, void* d_ws, size_t ws_size,
                              hipStream_t stream) {
  const float* feat = (const float*)d_in[0];
  const float* W1 = (const float*)d_in[1];
  const float* a1 = (const float*)d_in[2];
  const float* W2 = (const float*)d_in[3];
  const float* a2 = (const float*)d_in[4];
  const float* W3 = (const float*)d_in[5];
  const float* a3 = (const float*)d_in[6];
  const float* W4 = (const float*)d_in[7];
  const float* a4 = (const float*)d_in[8];
  const float* Wo = (const float*)d_in[9];
  float* ws = (float*)d_ws;
  float* out = (float*)d_out;

  k_weff<<<4, 256, 0, stream>>>(W1, a1, W2, a2, W3, a3, W4, a4, ws);
  k_main<<<BG * NSLICE, 256, 0, stream>>>(feat, ws);
  k_final<<<BG, 512, 0, stream>>>(W1, W2, W3, W4, Wo, ws, out);
}

// Round 8
// 119.014 us; speedup vs baseline: 1.5987x; 1.0221x over previous
//
#include <hip/hip_runtime.h>
#include <math.h>

// Problem constants (fixed by the reference)
#define BG     64      // b*g = 2*32 groups
#define NN     2048    // nodes per group
#define F      128     // IN_F == 2*OUT_F == 128
#define OUTF   64      // OUT_F
#define NSLICE 32      // node slices per group (64 nodes each)
#define SNODES 64      // nodes per slice

// Workspace layout (float offsets)
#define OFF_WEFF 0                                  // [4][128]
#define OFF_FP   512                                // [BG*NSLICE][4][128] partial pools
#define OFF_LP   (512 + BG * NSLICE * 4 * F)        // [BG*NSLICE][4] partial exp-sums

// ---------------------------------------------------------------------------
// K1: w_eff[h] = W_h @ a_h. One block per head, fully coalesced float4 W
// reads (R4 lesson: row-per-thread W reads are 16x line-amplified).
// score_n = (feat_n @ W) . a = feat_n . (W @ a); pooled = (sum p_n feat_n) @ W
// ---------------------------------------------------------------------------
__global__ __launch_bounds__(256) void k_weff(
    const float* __restrict__ W1, const float* __restrict__ a1,
    const float* __restrict__ W2, const float* __restrict__ a2,
    const float* __restrict__ W3, const float* __restrict__ a3,
    const float* __restrict__ W4, const float* __restrict__ a4,
    float* __restrict__ ws) {
  int h = blockIdx.x, t = threadIdx.x;
  const float* W = (h == 0) ? W1 : (h == 1) ? W2 : (h == 2) ? W3 : W4;
  const float* a = (h == 0) ? a1 : (h == 1) ? a2 : (h == 2) ? a3 : a4;
  __shared__ float aL[F];
  __shared__ float part[F][33];   // +1 pad: conflict-free row sums

  if (t < F) aL[t] = a[t];
  __syncthreads();

  int c = t & 31, r8 = t >> 5;    // chunk, row-octet
#pragma unroll
  for (int it = 0; it < 16; ++it) {
    int row = it * 8 + r8;
    float4 w = ((const float4*)(W + row * F))[c];
    part[row][c] = w.x * aL[4 * c] + w.y * aL[4 * c + 1] +
                   w.z * aL[4 * c + 2] + w.w * aL[4 * c + 3];
  }
  __syncthreads();

  if (t < F) {
    float s = 0.f;
#pragma unroll
    for (int c2 = 0; c2 < 32; ++c2) s += part[t][c2];
    ws[OFF_WEFF + h * F + t] = s;
  }
}

// ---------------------------------------------------------------------------
// K2: per-slice fused score/exp/pool, 64-node slices, ~39 KB LDS ->
// 4 blocks/CU (R7: occupancy was the limiter at 2 blocks/CU). XOR chunk
// swizzle (c ^ (n&31)) keeps all LDS b128 traffic <=2-way (free).
// Stage 1: 8 independent coalesced float4 loads/thread -> swizzled LDS.
// Stage 2: thread (n, h): one head dot + exp -> eLf.
// Stage 3: thread (i4, half, h): pool one head over 32 nodes.
// ---------------------------------------------------------------------------
__global__ __launch_bounds__(256) void k_main(
    const float* __restrict__ feat, float* __restrict__ ws) {
  int g = blockIdx.x >> 5;
  int slice = blockIdx.x & (NSLICE - 1);
  int t = threadIdx.x;

  __shared__ float4 sfeat[SNODES * 32];  // row n chunk c at n*32 + (c^(n&31))
  __shared__ float4 weffL[4 * 32];       // w_eff[h] chunk c at h*32 + c
  __shared__ float eLf[SNODES * 4];      // exp(score) [node][head]
  __shared__ float4 pacc[4][2][32];      // [head][half][i4]
  __shared__ float sePf[2][4];           // [half][head] exp-sum partials

  if (t < 128) weffL[t] = ((const float4*)(ws + OFF_WEFF))[t];

  // ---- Stage 1: global -> LDS (swizzled), 8 outstanding loads/thread ----
  const float4* fb =
      (const float4*)(feat + ((size_t)g * NN + slice * SNODES) * F);
  float4 ld[8];
#pragma unroll
  for (int k = 0; k < 8; ++k) ld[k] = fb[k * 256 + t];
#pragma unroll
  for (int k = 0; k < 8; ++k) {
    int j = k * 256 + t;
    int n = j >> 5, c = j & 31;
    sfeat[n * 32 + (c ^ (n & 31))] = ld[k];
  }
  __syncthreads();

  // ---- Stage 2: thread (n, h): one head dot + exp ----
  {
    int n = t & 63, h = t >> 6;
    int sw = n & 31, base = n * 32, wb = h * 32;
    float p = 0.f;
#pragma unroll 8
    for (int c = 0; c < 32; ++c) {
      float4 f = sfeat[base + (c ^ sw)];
      float4 w = weffL[wb + c];
      p += f.x * w.x + f.y * w.y + f.z * w.z + f.w * w.w;
    }
    // No max-subtraction: Xavier-bounded scores keep exp() in fp32 range.
    eLf[n * 4 + h] = __expf(p);
  }
  __syncthreads();

  // ---- Stage 3: thread (i4, half, h): pool one head over 32 nodes ----
  {
    int i4 = t & 31, q = (t >> 5) & 1, h = t >> 6;
    float4 a0 = make_float4(0.f, 0.f, 0.f, 0.f);
    float se = 0.f;
#pragma unroll 8
    for (int nn = 0; nn < 32; ++nn) {
      int n = q * 32 + nn;
      float4 f = sfeat[n * 32 + (i4 ^ (n & 31))];
      float e = eLf[n * 4 + h];
      a0.x += e * f.x; a0.y += e * f.y; a0.z += e * f.z; a0.w += e * f.w;
      se += e;
    }
    pacc[h][q][i4] = a0;
    if (i4 == 0) sePf[q][h] = se;
  }
  __syncthreads();

  // ---- Combine halves, write slice partials to ws ----
  if (t < 128) {
    int i4 = t & 31, h = t >> 5;
    float4 s0 = pacc[h][0][i4], s1 = pacc[h][1][i4];
    float4 s = make_float4(s0.x + s1.x, s0.y + s1.y,
                           s0.z + s1.z, s0.w + s1.w);
    ((float4*)(ws + OFF_FP))[(size_t)(g * NSLICE + slice) * 128 + h * 32 + i4] = s;
  }
  if (t == 0) {
    float4 L = make_float4(sePf[0][0] + sePf[1][0], sePf[0][1] + sePf[1][1],
                           sePf[0][2] + sePf[1][2], sePf[0][3] + sePf[1][3]);
    ((float4*)(ws + OFF_LP))[g * NSLICE + slice] = L;
  }
}

// ---------------------------------------------------------------------------
// K3: combine slice partials, normalize, pooled@W_h, concat@Wo, ELU.
// One block (512 threads) per group.
// ---------------------------------------------------------------------------
__global__ __launch_bounds__(512) void k_final(
    const float* __restrict__ W1, const float* __restrict__ W2,
    const float* __restrict__ W3, const float* __restrict__ W4,
    const float* __restrict__ Wo, const float* __restrict__ ws,
    float* __restrict__ out) {
  int g = blockIdx.x;
  int t = threadIdx.x;  // 0..511
  __shared__ float fp[512];
  __shared__ float multi[512];
  __shared__ float invl[4];
  __shared__ float part[8][64];

  if (t < 4) {
    float s = 0.f;
#pragma unroll
    for (int sl = 0; sl < NSLICE; ++sl)
      s += ws[OFF_LP + (g * NSLICE + sl) * 4 + t];
    invl[t] = 1.0f / s;
  }
  float s = 0.f;
  const float* fpb = ws + OFF_FP + (size_t)g * NSLICE * 512 + t;
#pragma unroll
  for (int sl = 0; sl < NSLICE; ++sl) s += fpb[sl * 512];
  __syncthreads();               // invl ready
  fp[t] = s * invl[t >> 7];      // pooled feature vector, normalized
  __syncthreads();

  // Stage 1: multi[h*128+col] = fp[h] . W_h[:,col]
  int h = t >> 7, col = t & 127;
  const float* W = (h == 0) ? W1 : (h == 1) ? W2 : (h == 2) ? W3 : W4;
  const float* fph = fp + h * F;
  float acc = 0.f;
#pragma unroll 16
  for (int i = 0; i < F; ++i) acc += fph[i] * W[i * F + col];
  multi[t] = acc;
  __syncthreads();

  // Stage 2: out[o] = elu(multi . Wo[:,o]); 8 partials per output column
  int o = t & 63, chunk = t >> 6;
  const float* mk = multi + chunk * 64;
  const float* wk = Wo + (size_t)chunk * 64 * OUTF + o;
  float p = 0.f;
#pragma unroll 16
  for (int k = 0; k < 64; ++k) p += mk[k] * wk[k * OUTF];
  part[chunk][o] = p;
  __syncthreads();

  if (t < 64) {
    float acc2 = 0.f;
#pragma unroll
    for (int c = 0; c < 8; ++c) acc2 += part[c][t];
    out[g * OUTF + t] = (acc2 > 0.f) ? acc2 : expm1f(acc2);
  }
}

// ---------------------------------------------------------------------------
extern "C" void kernel_launch(void* const* d_in, const int* in_sizes, int n_in,
                              void* d_out, int out_size, void* d_ws, size_t ws_size,
                              hipStream_t stream) {
  const float* feat = (const float*)d_in[0];
  const float* W1 = (const float*)d_in[1];
  const float* a1 = (const float*)d_in[2];
  const float* W2 = (const float*)d_in[3];
  const float* a2 = (const float*)d_in[4];
  const float* W3 = (const float*)d_in[5];
  const float* a3 = (const float*)d_in[6];
  const float* W4 = (const float*)d_in[7];
  const float* a4 = (const float*)d_in[8];
  const float* Wo = (const float*)d_in[9];
  float* ws = (float*)d_ws;
  float* out = (float*)d_out;

  k_weff<<<4, 256, 0, stream>>>(W1, a1, W2, a2, W3, a3, W4, a4, ws);
  k_main<<<BG * NSLICE, 256, 0, stream>>>(feat, ws);
  k_final<<<BG, 512, 0, stream>>>(W1, W2, W3, W4, Wo, ws, out);
}